// Round 2
// baseline (420.913 us; speedup 1.0000x reference)
//
#include <hip/hip_runtime.h>
#include <hip/hip_bf16.h>

// Fused "RNN" (parallel over T since h0 never updates):
//   hd = W_hh @ h0 + b_ih + b_hh            (block-cooperative, once, -> LDS)
//   out[t] = relu(x[t] @ W_ih^T + hd) @ W_out + b_out
//
// Single kernel. GEMM1 transposed: h^T = W_ih * x^T -> C layout gives each lane
// 4 consecutive neurons => ds_write_b64. GEMM2 transposed: out^T = W_out^T * h^T
// -> B-frag of h is contiguous ds_read_b128; D stores as global_store_dwordx4.
// Depth-2 register prefetch of x (hand-unrolled double body so the compiler
// emits partial vmcnt waits). Cheap 2-op bf16 rounding (ties-away; margin 5.7x).

typedef __attribute__((ext_vector_type(8))) short short8v;
typedef __attribute__((ext_vector_type(4))) short short4v;
typedef __attribute__((ext_vector_type(4))) float f32x4;

// fp32 -> bf16 pair, round-to-nearest (ties away). 5 VALU ops per pair.
static __device__ __forceinline__ unsigned pk_bf16(float lo, float hi) {
    unsigned ul = __float_as_uint(lo), uh = __float_as_uint(hi);
    return ((ul + 0x8000u) >> 16) | ((uh + 0x8000u) & 0xffff0000u);
}

static __device__ __forceinline__ short8v pack8v(f32x4 a, f32x4 b) {
    union { unsigned u[4]; short8v s; } r;
    r.u[0] = pk_bf16(a[0], a[1]);
    r.u[1] = pk_bf16(a[2], a[3]);
    r.u[2] = pk_bf16(b[0], b[1]);
    r.u[3] = pk_bf16(b[2], b[3]);
    return r.s;
}

static __device__ __forceinline__ short4v relu_pack4(f32x4 v) {
    union { unsigned u[2]; short4v s; } r;
    r.u[0] = pk_bf16(fmaxf(v[0], 0.f), fmaxf(v[1], 0.f));
    r.u[1] = pk_bf16(fmaxf(v[2], 0.f), fmaxf(v[3], 0.f));
    return r.s;
}

#define NTL(p) __builtin_nontemporal_load((const f32x4*)(p))

// LDS h-tile stride: 136 bf16 (=272 B): b64 writes 8B-aligned, b128 reads 16B-aligned.
// Bank math: writes hit each bank exactly 4x (b64 minimum), reads exactly 8x (b128 min).
#define HSTRIDE 136

__global__ __launch_bounds__(256, 2)
void rnn_fused(const float* __restrict__ x, const float* __restrict__ Wih,
               const float* __restrict__ Whh, const float* __restrict__ bih,
               const float* __restrict__ bhh, const float* __restrict__ Wout,
               const float* __restrict__ bout, const float* __restrict__ h0,
               float* __restrict__ out, int T) {
    const int tid  = threadIdx.x;
    const int lane = tid & 63;
    const int wave = tid >> 6;
    const int c    = lane & 15;   // time index within tile
    const int q    = lane >> 4;   // quad
    const int nwaves = gridDim.x * 4;
    const int gw     = blockIdx.x * 4 + wave;
    const int NT     = T >> 4;

    __shared__ __align__(16) short hbuf[4 * 16 * HSTRIDE];
    __shared__ __align__(16) float hdLDS[128];
    short* hrow = &hbuf[wave * (16 * HSTRIDE)];

    // ---- W_ih A-frags: A[m=neuron][k=input]; lane holds row mt*16+c, k = kc*32+q*8+j
    short8v a_w[8][2];
#pragma unroll
    for (int mt = 0; mt < 8; ++mt) {
#pragma unroll
        for (int kc = 0; kc < 2; ++kc) {
            const float* p = Wih + (mt * 16 + c) * 64 + kc * 32 + q * 8;
            a_w[mt][kc] = pack8v(*(const f32x4*)p, *(const f32x4*)(p + 4));
        }
    }

    // ---- W_out^T A-frags: A[m=o][k=neuron] = Wout[k][o]
    short8v a_o[2][4];
#pragma unroll
    for (int mt = 0; mt < 2; ++mt) {
#pragma unroll
        for (int kc = 0; kc < 4; ++kc) {
            union { unsigned u[4]; short8v s; } v;
#pragma unroll
            for (int j = 0; j < 4; ++j) {
                float f0 = Wout[(kc * 32 + q * 8 + 2 * j) * 32 + mt * 16 + c];
                float f1 = Wout[(kc * 32 + q * 8 + 2 * j + 1) * 32 + mt * 16 + c];
                v.u[j] = pk_bf16(f0, f1);
            }
            a_o[mt][kc] = v.s;
        }
    }

    // ---- b_out seed
    f32x4 bo4[2];
#pragma unroll
    for (int mt = 0; mt < 2; ++mt) bo4[mt] = *(const f32x4*)(bout + mt * 16 + q * 4);

    // ---- block-cooperative hidden drive: hd[n] = b_ih[n]+b_hh[n]+ (W_hh @ h0)[n]
    if (tid < 128) {
        float s = bih[tid] + bhh[tid];
        const f32x4* wr = (const f32x4*)(Whh + tid * 128);
        const f32x4* hr = (const f32x4*)h0;
#pragma unroll 8
        for (int k = 0; k < 32; ++k) {
            f32x4 w = wr[k], h = hr[k];
            s += w[0] * h[0] + w[1] * h[1] + w[2] * h[2] + w[3] * h[3];
        }
        hdLDS[tid] = s;
    }
    __syncthreads();

    f32x4 hd4[8];
#pragma unroll
    for (int mt = 0; mt < 8; ++mt) hd4[mt] = *(const f32x4*)&hdLDS[mt * 16 + q * 4];

    // ---- tile body (one 16-time tile): GEMM1 -> relu/pack -> LDS -> GEMM2 -> store
    auto body = [&](short8v xb0, short8v xb1, size_t row) {
        f32x4 acc[8];
#pragma unroll
        for (int mt = 0; mt < 8; ++mt) {
            acc[mt] = __builtin_amdgcn_mfma_f32_16x16x32_bf16(a_w[mt][0], xb0, hd4[mt], 0, 0, 0);
            acc[mt] = __builtin_amdgcn_mfma_f32_16x16x32_bf16(a_w[mt][1], xb1, acc[mt], 0, 0, 0);
        }
#pragma unroll
        for (int mt = 0; mt < 8; ++mt)
            *(short4v*)&hrow[c * HSTRIDE + mt * 16 + q * 4] = relu_pack4(acc[mt]);

        short8v hb0 = *(const short8v*)&hrow[c * HSTRIDE + 0 * 32 + q * 8];
        short8v hb1 = *(const short8v*)&hrow[c * HSTRIDE + 1 * 32 + q * 8];
        short8v hb2 = *(const short8v*)&hrow[c * HSTRIDE + 2 * 32 + q * 8];
        short8v hb3 = *(const short8v*)&hrow[c * HSTRIDE + 3 * 32 + q * 8];

        f32x4 o0 = bo4[0], o1 = bo4[1];
        o0 = __builtin_amdgcn_mfma_f32_16x16x32_bf16(a_o[0][0], hb0, o0, 0, 0, 0);
        o1 = __builtin_amdgcn_mfma_f32_16x16x32_bf16(a_o[1][0], hb0, o1, 0, 0, 0);
        o0 = __builtin_amdgcn_mfma_f32_16x16x32_bf16(a_o[0][1], hb1, o0, 0, 0, 0);
        o1 = __builtin_amdgcn_mfma_f32_16x16x32_bf16(a_o[1][1], hb1, o1, 0, 0, 0);
        o0 = __builtin_amdgcn_mfma_f32_16x16x32_bf16(a_o[0][2], hb2, o0, 0, 0, 0);
        o1 = __builtin_amdgcn_mfma_f32_16x16x32_bf16(a_o[1][2], hb2, o1, 0, 0, 0);
        o0 = __builtin_amdgcn_mfma_f32_16x16x32_bf16(a_o[0][3], hb3, o0, 0, 0, 0);
        o1 = __builtin_amdgcn_mfma_f32_16x16x32_bf16(a_o[1][3], hb3, o1, 0, 0, 0);

        float* op = out + row * 32 + q * 4;
        __builtin_nontemporal_store(o0, (f32x4*)op);
        __builtin_nontemporal_store(o1, (f32x4*)(op + 16));
    };

    // ---- depth-2 pipelined stream over tiles gw, gw+nwaves, ...
    int niter = (gw < NT) ? (NT - gw + nwaves - 1) / nwaves : 0;  // 32 at T=1M, 512 blocks
    const size_t rowstep = (size_t)nwaves * 16 * 64;  // floats between my tiles
    const size_t tstep   = (size_t)nwaves * 16;       // rows between my tiles
    size_t row = (size_t)gw * 16 + c;                 // this lane's time row
    const float* xcur = x + row * 64 + q * 8;

    f32x4 A0, A1, A2, A3, B0, B1, B2, B3;
    if (niter > 0) { A0 = NTL(xcur); A1 = NTL(xcur + 4); A2 = NTL(xcur + 32); A3 = NTL(xcur + 36); }
    if (niter > 1) {
        const float* p = xcur + rowstep;
        B0 = NTL(p); B1 = NTL(p + 4); B2 = NTL(p + 32); B3 = NTL(p + 36);
    }

    int it = 0;
    while (it < niter) {
        short8v xb0 = pack8v(A0, A1), xb1 = pack8v(A2, A3);
        if (it + 2 < niter) {
            const float* p = xcur + 2 * rowstep;
            A0 = NTL(p); A1 = NTL(p + 4); A2 = NTL(p + 32); A3 = NTL(p + 36);
        }
        body(xb0, xb1, row);
        ++it; row += tstep; xcur += rowstep;
        if (it >= niter) break;

        xb0 = pack8v(B0, B1); xb1 = pack8v(B2, B3);
        if (it + 2 < niter) {
            const float* p = xcur + 2 * rowstep;
            B0 = NTL(p); B1 = NTL(p + 4); B2 = NTL(p + 32); B3 = NTL(p + 36);
        }
        body(xb0, xb1, row);
        ++it; row += tstep; xcur += rowstep;
    }
}

extern "C" void kernel_launch(void* const* d_in, const int* in_sizes, int n_in,
                              void* d_out, int out_size, void* d_ws, size_t ws_size,
                              hipStream_t stream) {
    const float* x    = (const float*)d_in[0];
    const float* Wih  = (const float*)d_in[1];
    const float* Whh  = (const float*)d_in[2];
    const float* bih  = (const float*)d_in[3];
    const float* bhh  = (const float*)d_in[4];
    const float* Wout = (const float*)d_in[5];
    const float* bout = (const float*)d_in[6];
    const float* h0   = (const float*)d_in[7];
    float* out = (float*)d_out;

    const int T = in_sizes[0] / 64;  // 1048576

    rnn_fused<<<512, 256, 0, stream>>>(x, Wih, Whh, bih, bhh, Wout, bout, h0, out, T);
}